// Round 5
// baseline (8912.076 us; speedup 1.0000x reference)
//
#include <hip/hip_runtime.h>
#include <math.h>

#define NBLK 256
#define NTHR 256

typedef float vf4 __attribute__((ext_vector_type(4)));

namespace spinn {

constexpr int Ss = 48, Hh = 256, TT = 96, Mm = 193, H3 = 768, MLPD = 1024;

__device__ __forceinline__ float sigf(float x) { return 1.0f / (1.0f + expf(-x)); }

// ---- coherent access helpers (inline asm: avoids gfx950 flat-atomic bug,
// sc0 sc1 = device coherence point, never invalidates the caches that keep
// LDS-staging/private data hot) ----
__device__ __forceinline__ void st_co(float* p, float v) {
    asm volatile("global_store_dword %0, %1, off sc0 sc1" :: "v"(p), "v"(v) : "memory");
}
__device__ __forceinline__ unsigned ld_co_u32(const unsigned* p) {
    unsigned r;
    asm volatile("global_load_dword %0, %1, off sc0 sc1\n\t"
                 "s_waitcnt vmcnt(0)"
                 : "=&v"(r) : "v"(p) : "memory");
    return r;
}
__device__ __forceinline__ void ld_co1(const vf4* p0, vf4& r0) {
    asm volatile("global_load_dwordx4 %0, %1, off sc0 sc1\n\t"
                 "s_waitcnt vmcnt(0)"
                 : "=&v"(r0) : "v"(p0) : "memory");
}
// issue 4 coherent vf4 loads WITHOUT waiting (manual pipeline)
__device__ __forceinline__ void co_issue4(const float* p0, const float* p1,
                                          const float* p2, const float* p3,
                                          vf4& r0, vf4& r1, vf4& r2, vf4& r3) {
    asm volatile("global_load_dwordx4 %0, %4, off sc0 sc1\n\t"
                 "global_load_dwordx4 %1, %5, off sc0 sc1\n\t"
                 "global_load_dwordx4 %2, %6, off sc0 sc1\n\t"
                 "global_load_dwordx4 %3, %7, off sc0 sc1"
                 : "=&v"(r0), "=&v"(r1), "=&v"(r2), "=&v"(r3)
                 : "v"(p0), "v"(p1), "v"(p2), "v"(p3));
}
__device__ __forceinline__ void co_wait4(vf4& r0, vf4& r1, vf4& r2, vf4& r3) {
    asm volatile("s_waitcnt vmcnt(4)" : "+v"(r0), "+v"(r1), "+v"(r2), "+v"(r3));
}
__device__ __forceinline__ void co_wait0(vf4& r0, vf4& r1, vf4& r2, vf4& r3) {
    asm volatile("s_waitcnt vmcnt(0)" : "+v"(r0), "+v"(r1), "+v"(r2), "+v"(r3));
}

// ---- grid barrier: monotonic counter; arrival = fire-and-forget atomic,
// spin = coherent loads (no RMW convoy) ----
__device__ __forceinline__ void gbar(unsigned* cnt, unsigned tgt) {
    asm volatile("s_waitcnt vmcnt(0)" ::: "memory");
    __syncthreads();
    if (threadIdx.x == 0) {
        unsigned one = 1u;
        asm volatile("global_atomic_add %0, %1, off" :: "v"(cnt), "v"(one) : "memory");
        while (ld_co_u32(cnt) < tgt) __builtin_amdgcn_s_sleep(1);
    }
    __syncthreads();
}

__device__ __forceinline__ float wave_iscan(float v, int lane) {
    #pragma unroll
    for (int off = 1; off < 64; off <<= 1) {
        float u = __shfl_up(v, off, 64);
        if (lane >= off) v += u;
    }
    return v;
}
__device__ __forceinline__ float wred64(float v) {
    #pragma unroll
    for (int off = 1; off < 64; off <<= 1) v += __shfl_xor(v, off, 64);
    return v;
}

#define DOT_ACC(acc, wv, v)                                             \
    acc = fmaf((wv).x, (v).x, fmaf((wv).y, (v).y,                       \
          fmaf((wv).z, (v).z, fmaf((wv).w, (v).w, acc))));

}  // namespace spinn

using namespace spinn;

__global__ void __launch_bounds__(NTHR, 1) spinn_kernel(
    const int* __restrict__ x, const float* __restrict__ emb,
    const float* __restrict__ wih, const float* __restrict__ whh,
    const float* __restrict__ bih, const float* __restrict__ bhh,
    const float* __restrict__ aw, const float* __restrict__ ab,
    const float* __restrict__ tlw, const float* __restrict__ tlb,
    const float* __restrict__ trw, const float* __restrict__ trb,
    const float* __restrict__ l0w, const float* __restrict__ l0b,
    const float* __restrict__ l1w, const float* __restrict__ l1b,
    const float* __restrict__ l2w, const float* __restrict__ l2b,
    float* __restrict__ out, float* __restrict__ wsf, unsigned* __restrict__ bar)
{
    const int tid = threadIdx.x;
    const int b   = blockIdx.x;      // this block owns hidden dim b
    unsigned* cnt = bar;
    unsigned barnum = 0;

    // ---- global workspace ----
    float* XTg = wsf;                          // [64][768]
    float* Hg0 = XTg + 64 * H3;                // [64][256] h ping
    float* Hg1 = Hg0 + 64 * Hh;                // [64][256] h pong
    float* R1g = Hg1 + 64 * Hh;                // [64][256]
    float* R2g = R1g + 64 * Hh;                // [64][256]
    float* Y0g = R2g + 64 * Hh;                // [64][1024]
    float* Y1g = Y0g + 64 * MLPD;              // [64][1024]
    float* Vall = Y1g + 64 * MLPD;
    float* Vg  = Vall + (size_t)b * (64 * 200); // private V[e][200] (dim b)

    // ---- LDS ----
    __shared__ float s_wL[4 * 1024];   // LSTM rows {g*256+b}: [gate][768 xt | 256 h]
    __shared__ float s_wT[5 * 512];    // tree rows: [gate][256 left | 256 right]
    __shared__ float s_stk[64 * 200];  // stack strengths s[e][m]
    __shared__ float s_sb[64 * Ss];    // buffer strengths
    __shared__ float s_B[64 * Ss];     // buffer embeddings at dim b
    __shared__ float s_aw[512];        // alpha_w (full)
    __shared__ float s_c[64];          // LSTM c at dim b
    __shared__ float s_alpha[128];     // [e][2]
    __shared__ float s_r1d[64], s_r2d[64];
    __shared__ float s_xp1[64], s_xp2[64];
    __shared__ float s_wx[128];        // [e][2]: push weights at m=idx
    __shared__ float s_bias[4], s_tbias[5];
    __shared__ float s_scr[768];       // logit partials / l2 reduce

    const vf4* wL4 = (const vf4*)s_wL;
    const vf4* wT4 = (const vf4*)s_wT;
    const int lane = tid & 63, wid = tid >> 6;

    // ================= INIT =================
    {
        const vf4* wih4 = (const vf4*)wih;
        const vf4* whh4 = (const vf4*)whh;
        vf4* wL4w = (vf4*)s_wL;
        for (int i = tid; i < 4 * 192; i += NTHR) {
            int g = i / 192, kk = i - g * 192;
            wL4w[g * 256 + kk] = wih4[(size_t)(g * 256 + b) * 192 + kk];
        }
        for (int i = tid; i < 4 * 64; i += NTHR) {
            int g = i >> 6, kk = i & 63;
            wL4w[g * 256 + 192 + kk] = whh4[(size_t)(g * 256 + b) * 64 + kk];
        }
        const vf4* tlw4 = (const vf4*)tlw;
        const vf4* trw4 = (const vf4*)trw;
        vf4* wT4w = (vf4*)s_wT;
        for (int i = tid; i < 5 * 64; i += NTHR) {
            int g = i >> 6, kk = i & 63;
            wT4w[g * 128 + kk]      = tlw4[(size_t)(g * 256 + b) * 64 + kk];
            wT4w[g * 128 + 64 + kk] = trw4[(size_t)(g * 256 + b) * 64 + kk];
        }
        for (int i = tid; i < 512; i += NTHR) s_aw[i] = aw[i];
        if (tid < 4) s_bias[tid]  = bih[tid * 256 + b] + bhh[tid * 256 + b];
        if (tid < 5) s_tbias[tid] = tlb[tid * 256 + b] + trb[tid * 256 + b];
        for (int i = tid; i < 64 * 200; i += NTHR) s_stk[i] = 0.0f;
        if (tid < 64) s_c[tid] = 0.0f;
        for (int i = tid; i < 64 * Ss; i += NTHR) {
            int e = i / Ss, ss = i - e * Ss;
            int tok = x[e * Ss + ss];
            s_sb[i] = (tok > 0) ? 1.0f : 0.0f;
            s_B[i]  = emb[(size_t)tok * Hh + b];
        }
        vf4* vg4 = (vf4*)Vg;
        for (int i = tid; i < 64 * 50; i += NTHR) vg4[i] = (vf4){0.f, 0.f, 0.f, 0.f};
        {   // zero both h buffers (32768 floats over 65536 threads)
            int gi = b * NTHR + tid;
            if (gi < 2 * 64 * Hh) st_co(Hg0 + gi, 0.0f);
        }
        __syncthreads();
        // initial xt: x_b = read_buffer(ones); x1 = x2 = 0
        for (int e = wid * 16; e < wid * 16 + 16; e++) {
            float sbv = (lane < Ss) ? s_sb[e * Ss + lane] : 0.0f;
            float P = wave_iscan(sbv, lane);
            float wbe = fminf(P, 1.0f) - fminf(P - sbv, 1.0f);
            float be = (lane < Ss) ? s_B[e * Ss + lane] : 0.0f;
            float xb = wred64(wbe * be);
            if (lane == 0) {
                st_co(XTg + e * H3 + b, xb);
                st_co(XTg + e * H3 + 256 + b, 0.0f);
                st_co(XTg + e * H3 + 512 + b, 0.0f);
            }
        }
    }
    gbar(cnt, ++barnum * NBLK);

    // ================= time loop =================
    for (int t = 0; t < TT; t++) {
        const int par = t & 1;
        const float* Hprev = par ? Hg1 : Hg0;
        float* Hnext = par ? Hg0 : Hg1;
        const int idx = 191 - 2 * t, idx2 = idx - 1;

        // ---------- Phase L: LSTM gates (weights LDS-stationary) ----------
        {
            const int eg = tid >> 4, kc = tid & 15;
            const float* fb[4];
            #pragma unroll
            for (int i = 0; i < 4; i++) {
                int e = eg * 4 + i;
                fb[i] = (kc < 12) ? (XTg + e * H3) : (Hprev + e * Hh - H3);
            }
            float acc[4][4];
            #pragma unroll
            for (int r = 0; r < 4; r++)
                #pragma unroll
                for (int i = 0; i < 4; i++) acc[r][i] = 0.0f;

            auto bodyL = [&](int g, const vf4& v0, const vf4& v1, const vf4& v2, const vf4& v3) {
                const int kq = kc * 16 + ((g + kc) & 15);
                #pragma unroll
                for (int r = 0; r < 4; r++) {
                    vf4 wv = wL4[r * 256 + kq];
                    DOT_ACC(acc[r][0], wv, v0);
                    DOT_ACC(acc[r][1], wv, v1);
                    DOT_ACC(acc[r][2], wv, v2);
                    DOT_ACC(acc[r][3], wv, v3);
                }
            };
            vf4 A0, A1, A2, A3, B0, B1, B2, B3;
            {
                const int kv = kc * 64 + ((0 + kc) & 15) * 4;
                co_issue4(fb[0] + kv, fb[1] + kv, fb[2] + kv, fb[3] + kv, A0, A1, A2, A3);
            }
            #pragma unroll
            for (int g = 0; g < 16; g += 2) {
                { const int kv = kc * 64 + (((g + 1) + kc) & 15) * 4;
                  co_issue4(fb[0] + kv, fb[1] + kv, fb[2] + kv, fb[3] + kv, B0, B1, B2, B3); }
                co_wait4(A0, A1, A2, A3);
                bodyL(g, A0, A1, A2, A3);
                if (g + 2 < 16) {
                    const int kv = kc * 64 + (((g + 2) + kc) & 15) * 4;
                    co_issue4(fb[0] + kv, fb[1] + kv, fb[2] + kv, fb[3] + kv, A0, A1, A2, A3);
                    co_wait4(B0, B1, B2, B3);
                } else {
                    co_wait0(B0, B1, B2, B3);
                }
                bodyL(g + 1, B0, B1, B2, B3);
            }
            #pragma unroll
            for (int off = 1; off < 16; off <<= 1)
                #pragma unroll
                for (int r = 0; r < 4; r++)
                    #pragma unroll
                    for (int i = 0; i < 4; i++)
                        acc[r][i] += __shfl_xor(acc[r][i], off, 64);
            if (kc == 0) {
                #pragma unroll
                for (int i = 0; i < 4; i++) {
                    int e = eg * 4 + i;
                    float gi = acc[0][i] + s_bias[0], gf = acc[1][i] + s_bias[1];
                    float gg = acc[2][i] + s_bias[2], go = acc[3][i] + s_bias[3];
                    float cv = sigf(gf) * s_c[e] + sigf(gi) * tanhf(gg);
                    s_c[e] = cv;
                    float hv = sigf(go) * tanhf(cv);
                    st_co(Hnext + e * Hh + b, hv);
                }
            }
        }
        gbar(cnt, ++barnum * NBLK);

        // ---------- Phase T1: alphas, scans, r1/r2, buffer, x-partials ----------
        {
            {   // alpha logits: deterministic full-h dot (thread = (e, quarter))
                const int e = tid >> 2, q4 = tid & 3;
                const float* hb = Hnext + e * Hh + q4 * 64;
                vf4 A0, A1, A2, A3, B0, B1, B2, B3, C0, C1, C2, C3, D0, D1, D2, D3;
                co_issue4(hb + 0,  hb + 4,  hb + 8,  hb + 12, A0, A1, A2, A3);
                co_issue4(hb + 16, hb + 20, hb + 24, hb + 28, B0, B1, B2, B3);
                co_issue4(hb + 32, hb + 36, hb + 40, hb + 44, C0, C1, C2, C3);
                co_issue4(hb + 48, hb + 52, hb + 56, hb + 60, D0, D1, D2, D3);
                co_wait0(A0, A1, A2, A3);
                co_wait0(B0, B1, B2, B3);
                co_wait0(C0, C1, C2, C3);
                co_wait0(D0, D1, D2, D3);
                const vf4* aw0 = (const vf4*)s_aw + q4 * 16;
                const vf4* aw1 = (const vf4*)s_aw + 64 + q4 * 16;
                float p0 = 0.f, p1 = 0.f;
                vf4 hv[16] = {A0, A1, A2, A3, B0, B1, B2, B3, C0, C1, C2, C3, D0, D1, D2, D3};
                #pragma unroll
                for (int j = 0; j < 16; j++) {
                    DOT_ACC(p0, hv[j], aw0[j]);
                    DOT_ACC(p1, hv[j], aw1[j]);
                }
                s_scr[tid * 2] = p0;
                s_scr[tid * 2 + 1] = p1;
            }
            __syncthreads();
            if (tid < 64) {
                float l0v = s_scr[tid * 8] + s_scr[tid * 8 + 2] + s_scr[tid * 8 + 4] + s_scr[tid * 8 + 6] + ab[0];
                float l1v = s_scr[tid * 8 + 1] + s_scr[tid * 8 + 3] + s_scr[tid * 8 + 5] + s_scr[tid * 8 + 7] + ab[1];
                s_alpha[tid * 2]     = 1.0f / (1.0f + expf(10.0f * (l1v - l0v)));
                s_alpha[tid * 2 + 1] = 1.0f / (1.0f + expf(10.0f * (l0v - l1v)));
            }
            __syncthreads();

            for (int e = wid * 16; e < wid * 16 + 16; e++) {
                vf4 vv = (vf4){0.f, 0.f, 0.f, 0.f};
                if (lane < 50) vv = *((const vf4*)(Vg + e * 200) + lane);  // prefetch V
                float a_r = s_alpha[e * 2], a_s = s_alpha[e * 2 + 1];
                vf4 sv = (vf4){0.f, 0.f, 0.f, 0.f};
                if (lane < 50) sv = *((const vf4*)(s_stk + e * 200) + lane);
                float v0 = sv.x, v1 = sv.y, v2 = sv.z, v3 = sv.w;
                float c1 = v0 + v1, c2 = c1 + v2, c3 = c2 + v3;
                float inc = c3;
                #pragma unroll
                for (int off = 1; off < 64; off <<= 1) {
                    float u = __shfl_up(inc, off, 64);
                    if (lane >= off) inc += u;
                }
                float ex = inc - c3;
                float Pv[4] = {ex + v0, ex + c1, ex + c2, ex + c3};
                float Pp[4] = {ex, ex + v0, ex + c1, ex + c2};
                float vvv[4] = {v0, v1, v2, v3};
                const int m0 = lane * 4;
                float w1_[4], w2_[4], sn[4];
                #pragma unroll
                for (int i = 0; i < 4; i++) {
                    float w1 = fminf(Pv[i], a_r) - fminf(Pp[i], a_r);
                    float wt = fminf(Pv[i], 1.0f + a_r) - fminf(Pp[i], 1.0f + a_r);
                    w1_[i] = w1; w2_[i] = wt - w1;
                    float s2 = vvv[i] - wt;
                    int m = m0 + i;
                    if (m == idx)  s2 = a_r;
                    if (m == idx2) s2 = a_s;
                    sn[i] = s2;
                    if (m < Mm) s_stk[e * 200 + m] = s2;
                }
                float vx[4] = {vv.x, vv.y, vv.z, vv.w};
                float a1 = 0.f, a2 = 0.f;
                #pragma unroll
                for (int i = 0; i < 4; i++) {
                    a1 = fmaf(w1_[i], vx[i], a1);
                    a2 = fmaf(w2_[i], vx[i], a2);
                }
                a1 = wred64(a1); a2 = wred64(a2);
                if (lane == 0) {
                    st_co(R1g + e * Hh + b, a1);
                    st_co(R2g + e * Hh + b, a2);
                    s_r1d[e] = a1; s_r2d[e] = a2;
                }
                // push scan (alpha = 1) on updated s
                float d1 = sn[0] + sn[1], d2 = d1 + sn[2], d3 = d2 + sn[3];
                float inc2 = d3;
                #pragma unroll
                for (int off = 1; off < 64; off <<= 1) {
                    float u = __shfl_up(inc2, off, 64);
                    if (lane >= off) inc2 += u;
                }
                float ex2 = inc2 - d3;
                float Rv[4] = {ex2 + sn[0], ex2 + d1, ex2 + d2, ex2 + d3};
                float Rp[4] = {ex2, ex2 + sn[0], ex2 + d1, ex2 + d2};
                float w1e[4], w2e[4];
                #pragma unroll
                for (int i = 0; i < 4; i++) {
                    float u1 = fminf(Rv[i], 1.0f) - fminf(Rp[i], 1.0f);
                    float u2 = (fminf(Rv[i], 2.0f) - fminf(Rp[i], 2.0f)) - u1;
                    int m = m0 + i;
                    if (m == idx) { s_wx[e * 2] = u1; s_wx[e * 2 + 1] = u2; u1 = 0.f; u2 = 0.f; }
                    w1e[i] = u1; w2e[i] = u2;
                }
                // buffer pop + push
                float sbv = (lane < Ss) ? s_sb[e * Ss + lane] : 0.0f;
                float Pb = wave_iscan(sbv, lane);
                float wb = fminf(Pb, a_s) - fminf(Pb - sbv, a_s);
                float sbn = sbv - wb;
                if (lane < Ss) s_sb[e * Ss + lane] = sbn;
                float Pb2 = wave_iscan(sbn, lane);
                float wbe = fminf(Pb2, 1.0f) - fminf(Pb2 - sbn, 1.0f);
                float be = (lane < Ss) ? s_B[e * Ss + lane] : 0.0f;
                float bufv = wred64(wb * be);
                float xbv  = wred64(wbe * be);
                if (lane == 0) {
                    Vg[e * 200 + idx2] = bufv;           // private
                    st_co(XTg + e * H3 + b, xbv);        // x_b for next step
                }
                // x1/x2 partials (idx zero-weighted; idx2 via register bufv)
                float x1 = 0.f, x2 = 0.f;
                #pragma unroll
                for (int i = 0; i < 4; i++) {
                    int m = m0 + i;
                    float vm = (m == idx2) ? bufv : vx[i];
                    x1 = fmaf(w1e[i], vm, x1);
                    x2 = fmaf(w2e[i], vm, x2);
                }
                x1 = wred64(x1); x2 = wred64(x2);
                if (lane == 0) { s_xp1[e] = x1; s_xp2[e] = x2; }
            }
        }
        gbar(cnt, ++barnum * NBLK);

        // ---------- Phase T2: tree cell + finish xt ----------
        {
            const int eg = tid >> 4, kc = tid & 15;
            const float* fb[4];
            #pragma unroll
            for (int i = 0; i < 4; i++) {
                int e = eg * 4 + i;
                fb[i] = (kc < 8) ? (R1g + e * Hh) : (R2g + e * Hh - 256);
            }
            float acc[5][4];
            #pragma unroll
            for (int r = 0; r < 5; r++)
                #pragma unroll
                for (int i = 0; i < 4; i++) acc[r][i] = 0.0f;

            auto bodyT = [&](int g, const vf4& v0, const vf4& v1, const vf4& v2, const vf4& v3) {
                const int kq = kc * 8 + ((g + kc) & 7);
                #pragma unroll
                for (int r = 0; r < 5; r++) {
                    vf4 wv = wT4[r * 128 + kq];
                    DOT_ACC(acc[r][0], wv, v0);
                    DOT_ACC(acc[r][1], wv, v1);
                    DOT_ACC(acc[r][2], wv, v2);
                    DOT_ACC(acc[r][3], wv, v3);
                }
            };
            vf4 A0, A1, A2, A3, B0, B1, B2, B3;
            {
                const int kv = kc * 32 + ((0 + kc) & 7) * 4;
                co_issue4(fb[0] + kv, fb[1] + kv, fb[2] + kv, fb[3] + kv, A0, A1, A2, A3);
            }
            #pragma unroll
            for (int g = 0; g < 8; g += 2) {
                { const int kv = kc * 32 + (((g + 1) + kc) & 7) * 4;
                  co_issue4(fb[0] + kv, fb[1] + kv, fb[2] + kv, fb[3] + kv, B0, B1, B2, B3); }
                co_wait4(A0, A1, A2, A3);
                bodyT(g, A0, A1, A2, A3);
                if (g + 2 < 8) {
                    const int kv = kc * 32 + (((g + 2) + kc) & 7) * 4;
                    co_issue4(fb[0] + kv, fb[1] + kv, fb[2] + kv, fb[3] + kv, A0, A1, A2, A3);
                    co_wait4(B0, B1, B2, B3);
                } else {
                    co_wait0(B0, B1, B2, B3);
                }
                bodyT(g + 1, B0, B1, B2, B3);
            }
            #pragma unroll
            for (int off = 1; off < 16; off <<= 1)
                #pragma unroll
                for (int r = 0; r < 5; r++)
                    #pragma unroll
                    for (int i = 0; i < 4; i++)
                        acc[r][i] += __shfl_xor(acc[r][i], off, 64);
            if (kc == 0) {
                #pragma unroll
                for (int i = 0; i < 4; i++) {
                    int e = eg * 4 + i;
                    float ta  = acc[0][i] + s_tbias[0];
                    float ti  = acc[1][i] + s_tbias[1];
                    float tf1 = acc[2][i] + s_tbias[2];
                    float tf2 = acc[3][i] + s_tbias[3];
                    float to  = acc[4][i] + s_tbias[4];
                    float ct = tanhf(ta) * sigf(ti) + sigf(tf1) * s_r1d[e] + sigf(tf2) * s_r2d[e];
                    float ht = sigf(to) * tanhf(ct);
                    Vg[e * 200 + idx] = ht;  // private
                    float x1f = fmaf(s_wx[e * 2],     ht, s_xp1[e]);
                    float x2f = fmaf(s_wx[e * 2 + 1], ht, s_xp2[e]);
                    st_co(XTg + e * H3 + 256 + b, x1f);
                    st_co(XTg + e * H3 + 512 + b, x2f);
                }
            }
        }
        gbar(cnt, ++barnum * NBLK);
    }

    // ================= MLP head =================
    {   // layer 0: rows 4b..4b+3, input = XT[:,256:512]
        vf4* wW = (vf4*)s_wL;
        const vf4* l0w4 = (const vf4*)l0w;
        for (int i = tid; i < 256; i += NTHR)
            wW[i] = l0w4[(size_t)(4 * b) * 64 + i];
        __syncthreads();
        const int eg = tid >> 4, kc = tid & 15;
        float acc[4][4];
        #pragma unroll
        for (int r = 0; r < 4; r++)
            #pragma unroll
            for (int i = 0; i < 4; i++) acc[r][i] = 0.0f;
        const float* fb[4];
        #pragma unroll
        for (int i = 0; i < 4; i++) fb[i] = XTg + (eg * 4 + i) * H3 + 256 + kc * 16;
        vf4 A0, A1, A2, A3, B0, B1, B2, B3, C0, C1, C2, C3, D0, D1, D2, D3;
        co_issue4(fb[0] + 0,  fb[1] + 0,  fb[2] + 0,  fb[3] + 0,  A0, A1, A2, A3);
        co_issue4(fb[0] + 4,  fb[1] + 4,  fb[2] + 4,  fb[3] + 4,  B0, B1, B2, B3);
        co_issue4(fb[0] + 8,  fb[1] + 8,  fb[2] + 8,  fb[3] + 8,  C0, C1, C2, C3);
        co_issue4(fb[0] + 12, fb[1] + 12, fb[2] + 12, fb[3] + 12, D0, D1, D2, D3);
        co_wait0(A0, A1, A2, A3); co_wait0(B0, B1, B2, B3);
        co_wait0(C0, C1, C2, C3); co_wait0(D0, D1, D2, D3);
        vf4 vals[4][4] = {{A0, A1, A2, A3}, {B0, B1, B2, B3}, {C0, C1, C2, C3}, {D0, D1, D2, D3}};
        #pragma unroll
        for (int g = 0; g < 4; g++) {
            const int kq = kc * 4 + g;
            #pragma unroll
            for (int r = 0; r < 4; r++) {
                vf4 wv = ((const vf4*)s_wL)[r * 64 + kq];
                #pragma unroll
                for (int i = 0; i < 4; i++) DOT_ACC(acc[r][i], wv, vals[g][i]);
            }
        }
        #pragma unroll
        for (int off = 1; off < 16; off <<= 1)
            #pragma unroll
            for (int r = 0; r < 4; r++)
                #pragma unroll
                for (int i = 0; i < 4; i++)
                    acc[r][i] += __shfl_xor(acc[r][i], off, 64);
        if (kc == 0)
            #pragma unroll
            for (int r = 0; r < 4; r++)
                #pragma unroll
                for (int i = 0; i < 4; i++) {
                    int e = eg * 4 + i;
                    st_co(Y0g + e * MLPD + 4 * b + r, fmaxf(acc[r][i] + l0b[4 * b + r], 0.0f));
                }
    }
    gbar(cnt, ++barnum * NBLK);
    {   // layer 1: rows 4b..4b+3, K = 1024
        vf4* wW = (vf4*)s_wL;
        const vf4* l1w4 = (const vf4*)l1w;
        for (int i = tid; i < 1024; i += NTHR)
            wW[i] = l1w4[(size_t)(4 * b) * 256 + i];
        __syncthreads();
        const int eg = tid >> 4, kc = tid & 15;
        float acc[4][4];
        #pragma unroll
        for (int r = 0; r < 4; r++)
            #pragma unroll
            for (int i = 0; i < 4; i++) acc[r][i] = 0.0f;
        const float* fb[4];
        #pragma unroll
        for (int i = 0; i < 4; i++) fb[i] = Y0g + (eg * 4 + i) * MLPD;
        auto bodyM = [&](int g, const vf4& v0, const vf4& v1, const vf4& v2, const vf4& v3) {
            const int kq = kc * 16 + ((g + kc) & 15);
            #pragma unroll
            for (int r = 0; r < 4; r++) {
                vf4 wv = ((const vf4*)s_wL)[r * 256 + kq];
                DOT_ACC(acc[r][0], wv, v0);
                DOT_ACC(acc[r][1], wv, v1);
                DOT_ACC(acc[r][2], wv, v2);
                DOT_ACC(acc[r][3], wv, v3);
            }
        };
        vf4 A0, A1, A2, A3, B0, B1, B2, B3;
        {
            const int kv = kc * 64 + ((0 + kc) & 15) * 4;
            co_issue4(fb[0] + kv, fb[1] + kv, fb[2] + kv, fb[3] + kv, A0, A1, A2, A3);
        }
        #pragma unroll
        for (int g = 0; g < 16; g += 2) {
            { const int kv = kc * 64 + (((g + 1) + kc) & 15) * 4;
              co_issue4(fb[0] + kv, fb[1] + kv, fb[2] + kv, fb[3] + kv, B0, B1, B2, B3); }
            co_wait4(A0, A1, A2, A3);
            bodyM(g, A0, A1, A2, A3);
            if (g + 2 < 16) {
                const int kv = kc * 64 + (((g + 2) + kc) & 15) * 4;
                co_issue4(fb[0] + kv, fb[1] + kv, fb[2] + kv, fb[3] + kv, A0, A1, A2, A3);
                co_wait4(B0, B1, B2, B3);
            } else {
                co_wait0(B0, B1, B2, B3);
            }
            bodyM(g + 1, B0, B1, B2, B3);
        }
        #pragma unroll
        for (int off = 1; off < 16; off <<= 1)
            #pragma unroll
            for (int r = 0; r < 4; r++)
                #pragma unroll
                for (int i = 0; i < 4; i++)
                    acc[r][i] += __shfl_xor(acc[r][i], off, 64);
        if (kc == 0)
            #pragma unroll
            for (int r = 0; r < 4; r++)
                #pragma unroll
                for (int i = 0; i < 4; i++) {
                    int e = eg * 4 + i;
                    st_co(Y1g + e * MLPD + 4 * b + r, fmaxf(acc[r][i] + l1b[4 * b + r], 0.0f));
                }
    }
    gbar(cnt, ++barnum * NBLK);
    {   // layer 2: blocks b<64 each handle element b
        vf4* wW = (vf4*)s_wL;
        const vf4* l2w4 = (const vf4*)l2w;
        for (int i = tid; i < 768; i += NTHR) wW[i] = l2w4[i];
        __syncthreads();
        if (b < 64) {
            vf4 y;
            ld_co1((const vf4*)(Y1g + (size_t)b * MLPD) + tid, y);
            #pragma unroll
            for (int r = 0; r < 3; r++) {
                vf4 wv = ((const vf4*)s_wL)[r * 256 + tid];
                float p = 0.f;
                DOT_ACC(p, wv, y);
                s_scr[r * 256 + tid] = p;
            }
            __syncthreads();
            for (int off = 128; off >= 1; off >>= 1) {
                if (tid < off) {
                    #pragma unroll
                    for (int r = 0; r < 3; r++)
                        s_scr[r * 256 + tid] += s_scr[r * 256 + tid + off];
                }
                __syncthreads();
            }
            if (tid < 3) out[b * 3 + tid] = s_scr[tid * 256] + l2b[tid];
        }
    }
}

extern "C" void kernel_launch(void* const* d_in, const int* in_sizes, int n_in,
                              void* d_out, int out_size, void* d_ws, size_t ws_size,
                              hipStream_t stream) {
    (void)in_sizes; (void)n_in; (void)out_size; (void)ws_size;
    (void)hipMemsetAsync(d_ws, 0, 4096, stream);  // barrier counter

    const int*   x_   = (const int*)d_in[0];
    const float* emb  = (const float*)d_in[1];
    const float* wih  = (const float*)d_in[2];
    const float* whh  = (const float*)d_in[3];
    const float* bih  = (const float*)d_in[4];
    const float* bhh  = (const float*)d_in[5];
    const float* aw   = (const float*)d_in[6];
    const float* ab   = (const float*)d_in[7];
    const float* tlw  = (const float*)d_in[8];
    const float* tlb  = (const float*)d_in[9];
    const float* trw  = (const float*)d_in[10];
    const float* trb  = (const float*)d_in[11];
    const float* l0w  = (const float*)d_in[12];
    const float* l0b  = (const float*)d_in[13];
    const float* l1w  = (const float*)d_in[14];
    const float* l1b  = (const float*)d_in[15];
    const float* l2w  = (const float*)d_in[16];
    const float* l2b  = (const float*)d_in[17];

    float* wsf = (float*)((char*)d_ws + 4096);
    unsigned* bar = (unsigned*)d_ws;

    spinn_kernel<<<dim3(NBLK), dim3(NTHR), 0, stream>>>(
        x_, emb, wih, whh, bih, bhh, aw, ab, tlw, tlb, trw, trb,
        l0w, l0b, l1w, l1b, l2w, l2b, (float*)d_out, wsf, bar);
}

// Round 6
// 7327.227 us; speedup vs baseline: 1.2163x; 1.2163x over previous
//
#include <hip/hip_runtime.h>
#include <math.h>

#define NBLK 256
#define NTHR 256

typedef float vf4 __attribute__((ext_vector_type(4)));

namespace spinn {

constexpr int Bb = 64, Ss = 48, Hh = 256, TT = 96, Mm = 193, H3 = 768, MLPD = 1024;

__device__ __forceinline__ float sigf(float x) { return 1.0f / (1.0f + expf(-x)); }

#define FMA4(acc, a, b)                         \
    {                                           \
        acc.x = fmaf((a).x, (b).x, acc.x);      \
        acc.y = fmaf((a).y, (b).y, acc.y);      \
        acc.z = fmaf((a).z, (b).z, acc.z);      \
        acc.w = fmaf((a).w, (b).w, acc.w);      \
    }

// ---- coherent (device-scope) access helpers, inline asm (gfx950 flat-atomic
// backend bug workaround; sc0 sc1 = device coherence point; we never emit
// cache invalidates so per-XCD L2s keep read-only weights hot) ----
__device__ __forceinline__ void st_co(float* p, float v) {
    asm volatile("global_store_dword %0, %1, off sc0 sc1" :: "v"(p), "v"(v) : "memory");
}
__device__ __forceinline__ void st_co_u(unsigned* p, unsigned v) {
    asm volatile("global_store_dword %0, %1, off sc0 sc1" :: "v"(p), "v"(v) : "memory");
}
__device__ __forceinline__ unsigned ld_co_u32(const unsigned* p) {
    unsigned r;
    asm volatile("global_load_dword %0, %1, off sc0 sc1\n\t"
                 "s_waitcnt vmcnt(0)"
                 : "=&v"(r) : "v"(p) : "memory");
    return r;
}
__device__ __forceinline__ void ld_co_v4_1(const vf4* p0, vf4& r0) {
    asm volatile("global_load_dwordx4 %0, %1, off sc0 sc1\n\t"
                 "s_waitcnt vmcnt(0)"
                 : "=&v"(r0) : "v"(p0) : "memory");
}
__device__ __forceinline__ void ld_co_v4_2(const vf4* p0, const vf4* p1, vf4& r0, vf4& r1) {
    asm volatile("global_load_dwordx4 %0, %2, off sc0 sc1\n\t"
                 "global_load_dwordx4 %1, %3, off sc0 sc1\n\t"
                 "s_waitcnt vmcnt(0)"
                 : "=&v"(r0), "=&v"(r1) : "v"(p0), "v"(p1) : "memory");
}
__device__ __forceinline__ void ld_co_v4_3(const vf4* p0, const vf4* p1, const vf4* p2,
                                           vf4& r0, vf4& r1, vf4& r2) {
    asm volatile("global_load_dwordx4 %0, %3, off sc0 sc1\n\t"
                 "global_load_dwordx4 %1, %4, off sc0 sc1\n\t"
                 "global_load_dwordx4 %2, %5, off sc0 sc1\n\t"
                 "s_waitcnt vmcnt(0)"
                 : "=&v"(r0), "=&v"(r1), "=&v"(r2) : "v"(p0), "v"(p1), "v"(p2) : "memory");
}
__device__ __forceinline__ void ld_co_v4_4(const vf4* p0, const vf4* p1, const vf4* p2, const vf4* p3,
                                           vf4& r0, vf4& r1, vf4& r2, vf4& r3) {
    asm volatile("global_load_dwordx4 %0, %4, off sc0 sc1\n\t"
                 "global_load_dwordx4 %1, %5, off sc0 sc1\n\t"
                 "global_load_dwordx4 %2, %6, off sc0 sc1\n\t"
                 "global_load_dwordx4 %3, %7, off sc0 sc1\n\t"
                 "s_waitcnt vmcnt(0)"
                 : "=&v"(r0), "=&v"(r1), "=&v"(r2), "=&v"(r3)
                 : "v"(p0), "v"(p1), "v"(p2), "v"(p3) : "memory");
}
__device__ __forceinline__ void ld_co_f1x4(const float* p0, const float* p1, const float* p2,
                                           const float* p3, float& r0, float& r1, float& r2, float& r3) {
    asm volatile("global_load_dword %0, %4, off sc0 sc1\n\t"
                 "global_load_dword %1, %5, off sc0 sc1\n\t"
                 "global_load_dword %2, %6, off sc0 sc1\n\t"
                 "global_load_dword %3, %7, off sc0 sc1\n\t"
                 "s_waitcnt vmcnt(0)"
                 : "=&v"(r0), "=&v"(r1), "=&v"(r2), "=&v"(r3)
                 : "v"(p0), "v"(p1), "v"(p2), "v"(p3) : "memory");
}
// issue 4 coherent vf4 loads WITHOUT waiting (manual pipeline)
__device__ __forceinline__ void co_issue4(const float* p0, const float* p1,
                                          const float* p2, const float* p3,
                                          vf4& r0, vf4& r1, vf4& r2, vf4& r3) {
    asm volatile("global_load_dwordx4 %0, %4, off sc0 sc1\n\t"
                 "global_load_dwordx4 %1, %5, off sc0 sc1\n\t"
                 "global_load_dwordx4 %2, %6, off sc0 sc1\n\t"
                 "global_load_dwordx4 %3, %7, off sc0 sc1"
                 : "=&v"(r0), "=&v"(r1), "=&v"(r2), "=&v"(r3)
                 : "v"(p0), "v"(p1), "v"(p2), "v"(p3));
}
__device__ __forceinline__ void co_wait4(vf4& r0, vf4& r1, vf4& r2, vf4& r3) {
    asm volatile("s_waitcnt vmcnt(4)" : "+v"(r0), "+v"(r1), "+v"(r2), "+v"(r3));
}
__device__ __forceinline__ void co_wait0(vf4& r0, vf4& r1, vf4& r2, vf4& r3) {
    asm volatile("s_waitcnt vmcnt(0)" : "+v"(r0), "+v"(r1), "+v"(r2), "+v"(r3));
}

// ---- hierarchical grid barrier ----
// Arrivals: per-XCD counters (spread atomic contention). One leader per XCD
// per round (monotonic cmpswap election) polls the 8 arrival counters with a
// single batched 8-load; everyone else polls a per-XCD release flag that
// receives exactly ONE plain store per round (no RMW-vs-load serialization).
__device__ __forceinline__ unsigned gcas(unsigned* p, unsigned cmp, unsigned val) {
    unsigned long long dc = ((unsigned long long)cmp << 32) | (unsigned long long)val;
    unsigned old;
    asm volatile("global_atomic_cmpswap %0, %1, %2, off sc0\n\t"
                 "s_waitcnt vmcnt(0)"
                 : "=&v"(old) : "v"(p), "v"(dc) : "memory");
    return old;
}
__device__ __forceinline__ unsigned ld_sum8(const unsigned* base) {
    unsigned a0, a1, a2, a3, a4, a5, a6, a7;
    asm volatile("global_load_dword %0, %8, off sc0 sc1\n\t"
                 "global_load_dword %1, %8, off offset:128 sc0 sc1\n\t"
                 "global_load_dword %2, %8, off offset:256 sc0 sc1\n\t"
                 "global_load_dword %3, %8, off offset:384 sc0 sc1\n\t"
                 "global_load_dword %4, %8, off offset:512 sc0 sc1\n\t"
                 "global_load_dword %5, %8, off offset:640 sc0 sc1\n\t"
                 "global_load_dword %6, %8, off offset:768 sc0 sc1\n\t"
                 "global_load_dword %7, %8, off offset:896 sc0 sc1\n\t"
                 "s_waitcnt vmcnt(0)"
                 : "=&v"(a0), "=&v"(a1), "=&v"(a2), "=&v"(a3),
                   "=&v"(a4), "=&v"(a5), "=&v"(a6), "=&v"(a7)
                 : "v"(base) : "memory");
    return ((a0 + a1) + (a2 + a3)) + ((a4 + a5) + (a6 + a7));
}
__device__ __forceinline__ void gbar(unsigned* bar, unsigned xcd, unsigned barnum) {
    asm volatile("s_waitcnt vmcnt(0)" ::: "memory");  // drain my sc1 data stores
    __syncthreads();
    if (threadIdx.x == 0) {
        unsigned one = 1u;
        unsigned* arr = bar + (size_t)xcd * 32;
        asm volatile("global_atomic_add %0, %1, off" :: "v"(arr), "v"(one) : "memory");
        unsigned old = gcas(bar + 256 + (size_t)xcd * 32, barnum - 1, barnum);
        unsigned* rel = bar + 512 + (size_t)xcd * 32;
        if (old == barnum - 1) {            // leader for this XCD this round
            while (ld_sum8(bar) < barnum * NBLK) __builtin_amdgcn_s_sleep(2);
            st_co_u(rel, barnum);
        } else {                            // follower (incl. late arrivers)
            while (ld_co_u32(rel) < barnum) __builtin_amdgcn_s_sleep(1);
        }
    }
    __syncthreads();
}

// ---- wave-level (64-lane) primitives ----
__device__ __forceinline__ float wave_iscan(float v, int lane) {
    #pragma unroll
    for (int off = 1; off < 64; off <<= 1) {
        float u = __shfl_up(v, off, 64);
        if (lane >= off) v += u;
    }
    return v;
}
__device__ __forceinline__ float wred64(float v) {
    #pragma unroll
    for (int off = 1; off < 64; off <<= 1) v += __shfl_xor(v, off, 64);
    return v;
}
__device__ __forceinline__ float wred_ms(float v) {  // reduce over lane bits 4,5
    v += __shfl_xor(v, 16, 64);
    v += __shfl_xor(v, 32, 64);
    return v;
}

}  // namespace spinn

using namespace spinn;

__global__ void __launch_bounds__(NTHR, 1) spinn_kernel(
    const int* __restrict__ x, const float* __restrict__ emb,
    const float* __restrict__ wih, const float* __restrict__ whh,
    const float* __restrict__ bih, const float* __restrict__ bhh,
    const float* __restrict__ aw, const float* __restrict__ ab,
    const float* __restrict__ tlw, const float* __restrict__ tlb,
    const float* __restrict__ trw, const float* __restrict__ trb,
    const float* __restrict__ l0w, const float* __restrict__ l0b,
    const float* __restrict__ l1w, const float* __restrict__ l1b,
    const float* __restrict__ l2w, const float* __restrict__ l2b,
    float* __restrict__ out, float* __restrict__ wsf, unsigned* __restrict__ bar)
{
    const int tid = threadIdx.x;
    const int bid = blockIdx.x;
    const int eg = bid >> 4;          // element group (4 elements)
    const int q  = bid & 15;          // dim slice (16 dims)
    const int e0 = eg * 4;
    const int db = q * 16;

    unsigned xcd;
    asm volatile("s_getreg_b32 %0, hwreg(HW_REG_XCC_ID)" : "=s"(xcd));
    xcd &= 7;
    unsigned barnum = 0;

    // ---- global workspace (floats) ----
    float* XTg  = wsf;                          // [64][768]
    float* Hbg  = XTg + 64 * H3;                // [64][256]
    float* R1g  = Hbg + 64 * Hh;                // [64][256]
    float* R2g  = R1g + 64 * Hh;                // [64][256]
    float* Y0g  = R2g + 64 * Hh;                // [64][1024]
    float* Y1g  = Y0g + 64 * MLPD;              // [64][1024]
    float* Vall = Y1g + 64 * MLPD;
    float* Ball = Vall + (size_t)NBLK * (Mm * 64);
    float* Vg   = Vall + (size_t)bid * (Mm * 64);    // private [193][4 el][16 d]
    float* Bg   = Ball + (size_t)bid * (4 * Ss * 16); // private [4 el][48][16 d]

    // ---- LDS ----
    __shared__ float s_big[4096];
    __shared__ float s_h[1024];
    __shared__ float s_c[64];
    __shared__ float s_g[256];
    __shared__ float s_tg[320];
    __shared__ float s_s[800];
    __shared__ float s_sb[192];
    __shared__ float sw1[800], sw2[800];
    __shared__ float s_wb[192], s_wbe[192];
    __shared__ float s_wx[16];
    __shared__ float s_xp1[64], s_xp2[64], s_xpb[64];

    float* s_xt = s_big;             // [4][768]
    float* s_r1 = s_big;             // [4][256]
    float* s_r2 = s_big + 1024;      // [4][256]

    const int lane = tid & 63;
    const int elw  = tid >> 6;
    const int ms   = lane >> 4;
    const int dl   = lane & 15;

    // ================= INIT =================
    {
        for (int i = tid; i < 4 * Ss * 16; i += NTHR) {
            int el = i / (Ss * 16);
            int rem = i - el * (Ss * 16);
            int s = rem >> 4, d = rem & 15;
            int tok = x[(e0 + el) * Ss + s];
            Bg[i] = emb[(size_t)tok * Hh + db + d];
        }
        if (tid < 4 * Ss) {
            int el = tid / Ss, s = tid % Ss;
            s_sb[tid] = (x[(e0 + el) * Ss + s] > 0) ? 1.0f : 0.0f;
        }
        for (int i = tid; i < 800; i += NTHR) s_s[i] = 0.0f;
        for (int i = tid; i < 1024; i += NTHR) s_h[i] = 0.0f;
        if (tid < 64) s_c[tid] = 0.0f;
        for (int i = tid; i < Mm * 64; i += NTHR) Vg[i] = 0.0f;
        asm volatile("s_waitcnt vmcnt(0)" ::: "memory");
        __syncthreads();
        float sbv = (lane < Ss) ? s_sb[elw * Ss + lane] : 0.0f;
        float P = wave_iscan(sbv, lane);
        float wbe = fminf(P, 1.0f) - fminf(P - sbv, 1.0f);
        if (lane < Ss) s_wbe[elw * Ss + lane] = wbe;
        __syncthreads();
        float axb = 0.0f;
        for (int t2 = ms * 12; t2 < ms * 12 + 12; t2++)
            axb = fmaf(s_wbe[elw * Ss + t2], Bg[elw * (Ss * 16) + t2 * 16 + dl], axb);
        axb = wred_ms(axb);
        if (lane < 16) {
            float* xte = XTg + (size_t)(e0 + elw) * H3;
            st_co(xte + db + dl, axb);
            st_co(xte + 256 + db + dl, 0.0f);
            st_co(xte + 512 + db + dl, 0.0f);
        }
    }
    gbar(bar, xcd, ++barnum);

    // ================= time loop =================
    for (int t = 0; t < TT; t++) {
        const int idx  = 191 - 2 * t;
        const int idx2 = idx - 1;

        // ---------- Phase L: LSTM ----------
        {
            const vf4* src = (const vf4*)XTg + (size_t)e0 * 192;
            vf4 a, b, c;
            ld_co_v4_3(src + tid, src + tid + 256, src + tid + 512, a, b, c);
            vf4* sx4 = (vf4*)s_xt;
            sx4[tid] = a; sx4[tid + 256] = b; sx4[tid + 512] = c;
            __syncthreads();
            int r = tid & 63, g = r >> 4, d = r & 15;
            int row = g * Hh + db + d;
            const vf4* w4  = (const vf4*)wih + (size_t)row * 192;
            const vf4* x4  = (const vf4*)s_xt + elw * 192;
            const vf4* wh4 = (const vf4*)whh + (size_t)row * 64;
            const vf4* h4  = (const vf4*)s_h + elw * 64;
            vf4 acc4 = {0.f, 0.f, 0.f, 0.f};
            #pragma unroll 4
            for (int k = 0; k < 192; k++) { vf4 wv = w4[k], xv = x4[k]; FMA4(acc4, wv, xv); }
            #pragma unroll 4
            for (int k = 0; k < 64; k++)  { vf4 wv = wh4[k], hv = h4[k]; FMA4(acc4, wv, hv); }
            s_g[elw * 64 + g * 16 + d] = bih[row] + bhh[row] + acc4.x + acc4.y + acc4.z + acc4.w;
            __syncthreads();
            if (tid < 64) {
                int el2 = tid >> 4, d2 = tid & 15;
                float gi = s_g[el2 * 64 + d2], gf = s_g[el2 * 64 + 16 + d2];
                float gg = s_g[el2 * 64 + 32 + d2], go = s_g[el2 * 64 + 48 + d2];
                float cv = sigf(gf) * s_c[tid] + sigf(gi) * tanhf(gg);
                s_c[tid] = cv;
                float hv = sigf(go) * tanhf(cv);
                st_co(Hbg + (size_t)(e0 + el2) * Hh + db + d2, hv);
            }
        }
        gbar(bar, xcd, ++barnum);

        // ---------- Phase T1 (per-wave; wave = element) ----------
        {
            const int e = e0 + elw;
            float h0, h1, h2, h3;
            const float* hb = Hbg + (size_t)e * Hh + lane;
            ld_co_f1x4(hb, hb + 64, hb + 128, hb + 192, h0, h1, h2, h3);
            s_h[elw * Hh + lane] = h0;       s_h[elw * Hh + 64 + lane] = h1;
            s_h[elw * Hh + 128 + lane] = h2; s_h[elw * Hh + 192 + lane] = h3;
            float lg0 = h0 * aw[lane] + h1 * aw[64 + lane] + h2 * aw[128 + lane] + h3 * aw[192 + lane];
            float lg1 = h0 * aw[256 + lane] + h1 * aw[320 + lane] + h2 * aw[384 + lane] + h3 * aw[448 + lane];
            lg0 = wred64(lg0) + ab[0];
            lg1 = wred64(lg1) + ab[1];
            float a_r = 1.0f / (1.0f + expf(10.0f * (lg1 - lg0)));
            float a_s = 1.0f / (1.0f + expf(10.0f * (lg0 - lg1)));
            // stack pop-scan
            float sval = (lane * 4 < Mm) ? 1.0f : 0.0f;  // placeholder to keep reg shape
            (void)sval;
            int m0 = lane * 4;
            float v0 = (m0     < Mm) ? s_s[elw * 200 + m0]     : 0.0f;
            float v1 = (m0 + 1 < Mm) ? s_s[elw * 200 + m0 + 1] : 0.0f;
            float v2 = (m0 + 2 < Mm) ? s_s[elw * 200 + m0 + 2] : 0.0f;
            float v3 = (m0 + 3 < Mm) ? s_s[elw * 200 + m0 + 3] : 0.0f;
            float c1 = v0 + v1, c2 = c1 + v2, c3 = c2 + v3;
            float inc = c3;
            #pragma unroll
            for (int off = 1; off < 64; off <<= 1) {
                float u = __shfl_up(inc, off, 64);
                if (lane >= off) inc += u;
            }
            float ex = inc - c3;
            float Pv[4]  = {ex + v0, ex + c1, ex + c2, ex + c3};
            float Pp[4]  = {ex, ex + v0, ex + c1, ex + c2};
            float vv_[4] = {v0, v1, v2, v3};
            float sn[4];
            #pragma unroll
            for (int i = 0; i < 4; i++) {
                int m = m0 + i;
                float w1 = fminf(Pv[i], a_r) - fminf(Pp[i], a_r);
                float wt = fminf(Pv[i], 1.0f + a_r) - fminf(Pp[i], 1.0f + a_r);
                float s2 = vv_[i] - wt;
                if (m == idx) s2 = a_r;
                if (m == idx2) s2 = a_s;
                sn[i] = s2;
                if (m < Mm) {
                    sw1[elw * 200 + m] = w1;
                    sw2[elw * 200 + m] = wt - w1;
                    s_s[elw * 200 + m] = s2;
                }
            }
            __syncthreads();
            // r1/r2 dots (lane = ms*16+dl, m-split by ms)
            int mA = ms * 48, mB = (ms == 3) ? Mm : (mA + 48);
            float a1 = 0.0f, a2 = 0.0f;
            for (int m = mA; m < mB; m++) {
                float vv = Vg[m * 64 + elw * 16 + dl];
                a1 = fmaf(sw1[elw * 200 + m], vv, a1);
                a2 = fmaf(sw2[elw * 200 + m], vv, a2);
            }
            a1 = wred_ms(a1); a2 = wred_ms(a2);
            if (lane < 16) {
                st_co(R1g + (size_t)e * Hh + db + dl, a1);
                st_co(R2g + (size_t)e * Hh + db + dl, a2);
            }
            // push scan (alpha = 1) on updated s
            float d1 = sn[0] + sn[1], d2 = d1 + sn[2], d3 = d2 + sn[3];
            float inc2 = d3;
            #pragma unroll
            for (int off = 1; off < 64; off <<= 1) {
                float u = __shfl_up(inc2, off, 64);
                if (lane >= off) inc2 += u;
            }
            float ex2 = inc2 - d3;
            float Qv[4] = {ex2 + sn[0], ex2 + d1, ex2 + d2, ex2 + d3};
            float Qp[4] = {ex2, ex2 + sn[0], ex2 + d1, ex2 + d2};
            #pragma unroll
            for (int i = 0; i < 4; i++) {
                int m = m0 + i;
                float w1e = fminf(Qv[i], 1.0f) - fminf(Qp[i], 1.0f);
                float w2e = (fminf(Qv[i], 2.0f) - fminf(Qp[i], 2.0f)) - w1e;
                if (m == idx)  { s_wx[elw * 4 + 0] = w1e; s_wx[elw * 4 + 1] = w2e; w1e = 0.0f; w2e = 0.0f; }
                if (m == idx2) { s_wx[elw * 4 + 2] = w1e; s_wx[elw * 4 + 3] = w2e; w1e = 0.0f; w2e = 0.0f; }
                if (m < Mm) { sw1[elw * 200 + m] = w1e; sw2[elw * 200 + m] = w2e; }
            }
            // buffer pop + push scans
            float sbv = (lane < Ss) ? s_sb[elw * Ss + lane] : 0.0f;
            float Pb = wave_iscan(sbv, lane);
            float wb = fminf(Pb, a_s) - fminf(Pb - sbv, a_s);
            float sbn = sbv - wb;
            float Pb2 = wave_iscan(sbn, lane);
            float wbe = fminf(Pb2, 1.0f) - fminf(Pb2 - sbn, 1.0f);
            if (lane < Ss) {
                s_sb[elw * Ss + lane] = sbn;
                s_wb[elw * Ss + lane] = wb;
                s_wbe[elw * Ss + lane] = wbe;
            }
            __syncthreads();
            float abf = 0.0f, axb = 0.0f;
            for (int t2 = ms * 12; t2 < ms * 12 + 12; t2++) {
                float be = Bg[elw * (Ss * 16) + t2 * 16 + dl];
                abf = fmaf(s_wb[elw * Ss + t2], be, abf);
                axb = fmaf(s_wbe[elw * Ss + t2], be, axb);
            }
            abf = wred_ms(abf); axb = wred_ms(axb);
            if (lane < 16) Vg[idx2 * 64 + elw * 16 + dl] = abf;  // private store
            // x1/x2 partial dots
            float x1 = 0.0f, x2 = 0.0f;
            for (int m = mA; m < mB; m++) {
                float vv = Vg[m * 64 + elw * 16 + dl];
                x1 = fmaf(sw1[elw * 200 + m], vv, x1);
                x2 = fmaf(sw2[elw * 200 + m], vv, x2);
            }
            if (ms == 0) {
                x1 = fmaf(s_wx[elw * 4 + 2], abf, x1);
                x2 = fmaf(s_wx[elw * 4 + 3], abf, x2);
            }
            x1 = wred_ms(x1); x2 = wred_ms(x2);
            if (lane < 16) {
                s_xp1[elw * 16 + dl] = x1;
                s_xp2[elw * 16 + dl] = x2;
                s_xpb[elw * 16 + dl] = axb;
            }
        }
        gbar(bar, xcd, ++barnum);

        // ---------- Phase T2: tree cell, V[idx] write, next xt ----------
        {
            const vf4* pR1 = (const vf4*)R1g + (size_t)e0 * 64 + tid;
            const vf4* pR2 = (const vf4*)R2g + (size_t)e0 * 64 + tid;
            vf4 ra, rb;
            ld_co_v4_2(pR1, pR2, ra, rb);
            ((vf4*)s_r1)[tid] = ra;
            ((vf4*)s_r2)[tid] = rb;
            __syncthreads();
            {
                int r = tid & 63, g = r >> 4, d = r & 15;
                int row = g * Hh + db + d;
                const vf4* wl = (const vf4*)tlw + (size_t)row * 64;
                const vf4* wr = (const vf4*)trw + (size_t)row * 64;
                const vf4* p1 = (const vf4*)s_r1 + elw * 64;
                const vf4* p2 = (const vf4*)s_r2 + elw * 64;
                vf4 acc4 = {0.f, 0.f, 0.f, 0.f};
                #pragma unroll 4
                for (int k = 0; k < 64; k++) {
                    vf4 w1v = wl[k], r1v = p1[k]; FMA4(acc4, w1v, r1v);
                    vf4 w2v = wr[k], r2v = p2[k]; FMA4(acc4, w2v, r2v);
                }
                s_tg[elw * 80 + g * 16 + d] =
                    tlb[row] + trb[row] + acc4.x + acc4.y + acc4.z + acc4.w;
            }
            if (tid < 64) {
                int el2 = tid >> 4, d2 = tid & 15;
                int row = 4 * Hh + db + d2;
                const vf4* wl = (const vf4*)tlw + (size_t)row * 64;
                const vf4* wr = (const vf4*)trw + (size_t)row * 64;
                const vf4* p1 = (const vf4*)s_r1 + el2 * 64;
                const vf4* p2 = (const vf4*)s_r2 + el2 * 64;
                vf4 acc4 = {0.f, 0.f, 0.f, 0.f};
                #pragma unroll 4
                for (int k = 0; k < 64; k++) {
                    vf4 w1v = wl[k], r1v = p1[k]; FMA4(acc4, w1v, r1v);
                    vf4 w2v = wr[k], r2v = p2[k]; FMA4(acc4, w2v, r2v);
                }
                s_tg[el2 * 80 + 64 + d2] =
                    tlb[row] + trb[row] + acc4.x + acc4.y + acc4.z + acc4.w;
            }
            __syncthreads();
            if (tid < 64) {
                int el2 = tid >> 4, d2 = tid & 15;
                int e = e0 + el2;
                float ta  = s_tg[el2 * 80 + d2];
                float ti  = s_tg[el2 * 80 + 16 + d2];
                float tf1 = s_tg[el2 * 80 + 32 + d2];
                float tf2 = s_tg[el2 * 80 + 48 + d2];
                float to  = s_tg[el2 * 80 + 64 + d2];
                float r1d = s_r1[el2 * Hh + db + d2];
                float r2d = s_r2[el2 * Hh + db + d2];
                float ct = tanhf(ta) * sigf(ti) + sigf(tf1) * r1d + sigf(tf2) * r2d;
                float ht = sigf(to) * tanhf(ct);
                Vg[idx * 64 + el2 * 16 + d2] = ht;  // private
                float x1f = fmaf(s_wx[el2 * 4 + 0], ht, s_xp1[tid]);
                float x2f = fmaf(s_wx[el2 * 4 + 1], ht, s_xp2[tid]);
                float* xte = XTg + (size_t)e * H3;
                st_co(xte + db + d2, s_xpb[tid]);
                st_co(xte + 256 + db + d2, x1f);
                st_co(xte + 512 + db + d2, x2f);
            }
        }
        gbar(bar, xcd, ++barnum);
    }

    // ================= MLP head =================
    {   // layer 0: input = XT[:, 256:512]
        int j = tid & 63;
        const vf4* px = (const vf4*)XTg + (size_t)(e0 + elw) * 192 + 64 + j;
        vf4 xv;
        ld_co_v4_1(px, xv);
        ((vf4*)s_r1)[elw * 64 + j] = xv;
        __syncthreads();
        int row = q * 64 + (tid & 63);
        const vf4* w = (const vf4*)l0w + (size_t)row * 64;
        const vf4* xx = (const vf4*)s_r1 + elw * 64;
        vf4 acc4 = {0.f, 0.f, 0.f, 0.f};
        #pragma unroll 4
        for (int k = 0; k < 64; k++) { vf4 wv = w[k], v = xx[k]; FMA4(acc4, wv, v); }
        float y = fmaxf(l0b[row] + acc4.x + acc4.y + acc4.z + acc4.w, 0.0f);
        st_co(Y0g + (size_t)(e0 + elw) * MLPD + row, y);
    }
    gbar(bar, xcd, ++barnum);
    {   // layer 1
        const vf4* p = (const vf4*)Y0g + (size_t)e0 * 256;
        vf4 y0, y1, y2, y3;
        ld_co_v4_4(p + tid, p + tid + 256, p + tid + 512, p + tid + 768, y0, y1, y2, y3);
        vf4* sy = (vf4*)s_big;
        sy[tid] = y0; sy[tid + 256] = y1; sy[tid + 512] = y2; sy[tid + 768] = y3;
        __syncthreads();
        int row = q * 64 + (tid & 63);
        const vf4* w = (const vf4*)l1w + (size_t)row * 256;
        const vf4* yy = sy + elw * 256;
        vf4 acc4 = {0.f, 0.f, 0.f, 0.f};
        #pragma unroll 4
        for (int k = 0; k < 256; k++) { vf4 wv = w[k], v = yy[k]; FMA4(acc4, wv, v); }
        float y = fmaxf(l1b[row] + acc4.x + acc4.y + acc4.z + acc4.w, 0.0f);
        st_co(Y1g + (size_t)(e0 + elw) * MLPD + row, y);
    }
    gbar(bar, xcd, ++barnum);
    if (q < 4) {  // layer 2: block (eg, q=el) handles element e0+q
        int e = e0 + q;
        const vf4* p = (const vf4*)Y1g + (size_t)e * 256 + tid;
        vf4 yv;
        ld_co_v4_1(p, yv);
        #pragma unroll
        for (int r = 0; r < 3; r++) {
            const float* w = l2w + (size_t)r * MLPD + tid * 4;
            s_h[r * 256 + tid] = yv.x * w[0] + yv.y * w[1] + yv.z * w[2] + yv.w * w[3];
        }
        __syncthreads();
        for (int off = 128; off >= 1; off >>= 1) {
            if (tid < off) {
                #pragma unroll
                for (int r = 0; r < 3; r++)
                    s_h[r * 256 + tid] += s_h[r * 256 + tid + off];
            }
            __syncthreads();
        }
        if (tid < 3) out[e * 3 + tid] = s_h[tid * 256] + l2b[tid];
    }
}

extern "C" void kernel_launch(void* const* d_in, const int* in_sizes, int n_in,
                              void* d_out, int out_size, void* d_ws, size_t ws_size,
                              hipStream_t stream) {
    (void)in_sizes; (void)n_in; (void)out_size; (void)ws_size;
    (void)hipMemsetAsync(d_ws, 0, 4096, stream);  // arrival/claim/release cells

    const int*   x_   = (const int*)d_in[0];
    const float* emb  = (const float*)d_in[1];
    const float* wih  = (const float*)d_in[2];
    const float* whh  = (const float*)d_in[3];
    const float* bih  = (const float*)d_in[4];
    const float* bhh  = (const float*)d_in[5];
    const float* aw   = (const float*)d_in[6];
    const float* ab   = (const float*)d_in[7];
    const float* tlw  = (const float*)d_in[8];
    const float* tlb  = (const float*)d_in[9];
    const float* trw  = (const float*)d_in[10];
    const float* trb  = (const float*)d_in[11];
    const float* l0w  = (const float*)d_in[12];
    const float* l0b  = (const float*)d_in[13];
    const float* l1w  = (const float*)d_in[14];
    const float* l1b  = (const float*)d_in[15];
    const float* l2w  = (const float*)d_in[16];
    const float* l2b  = (const float*)d_in[17];

    float* wsf = (float*)((char*)d_ws + 4096);
    unsigned* bar = (unsigned*)d_ws;

    spinn_kernel<<<dim3(NBLK), dim3(NTHR), 0, stream>>>(
        x_, emb, wih, whh, bih, bhh, aw, ab, tlw, tlb, trw, trb,
        l0w, l0b, l1w, l1b, l2w, l2b, (float*)d_out, wsf, bar);
}